// Round 3
// baseline (276.617 us; speedup 1.0000x reference)
//
#include <hip/hip_runtime.h>

typedef unsigned int u32;
typedef unsigned short u16;
typedef unsigned long long u64;

typedef __attribute__((ext_vector_type(4))) float f32x4;
typedef __attribute__((ext_vector_type(8))) __bf16 bf16x8;
typedef __attribute__((ext_vector_type(8))) u16 u16x8;
typedef __attribute__((ext_vector_type(4))) u16 u16x4;

#define NB 256
#define ND 512
#define NC 100000
#define NBLK 782               // ceil(NC/128)
#define CAP 524288             // u64 collect entries (4 MB)
#define THRC 0.08f             // static collect threshold << neg_th (~0.13+)
#define EXP2K 92.33248261689366f   // 64*log2(e)

// ---- ws layout (bytes) ----
#define OFF_EMBN  0            // u16 [256*512] = 262144
#define OFF_TGT   262144       // f32 [256]
#define OFF_SEXP  263168       // f32 [256]
#define OFF_AMAX  264192       // u64 [256] = 2048
#define OFF_SCAL  266240       // u32 {topk, bufcnt} (16B)
#define OFF_PART  266496       // f32 [256][800] = 819200
#define OFF_BUF   1085696      // u64 [CAP] = 4194304

__device__ __forceinline__ u32 ordkey(float f) {
  u32 u = __float_as_uint(f);
  return (u & 0x80000000u) ? ~u : (u | 0x80000000u);
}
__device__ __forceinline__ float inv_ordkey(u32 key) {
  u32 u = (key & 0x80000000u) ? (key & 0x7FFFFFFFu) : ~key;
  return __uint_as_float(u);
}
__device__ __forceinline__ u16 f2bf(float x) {  // RNE f32->bf16
  u32 u = __float_as_uint(x);
  return (u16)((u + 0x7FFFu + ((u >> 16) & 1u)) >> 16);
}
__device__ __forceinline__ float bf2f(u16 h) {
  return __uint_as_float(((u32)h) << 16);
}

// ---------------- K0: normalize embedding rows -> bf16 ----------------
__global__ void k_prep(const float* __restrict__ emb, u16* __restrict__ embn) {
  __shared__ float s[128];
  const int r = blockIdx.x, t = threadIdx.x;
  float4 v = *(const float4*)(emb + r * ND + t * 4);
  s[t] = v.x * v.x + v.y * v.y + v.z * v.z + v.w * v.w;
  __syncthreads();
  for (int st = 64; st > 0; st >>= 1) { if (t < st) s[t] += s[t + st]; __syncthreads(); }
  const float rinv = 1.0f / sqrtf(s[0]);
  u16x4 o = { f2bf(v.x * rinv), f2bf(v.y * rinv), f2bf(v.z * rinv), f2bf(v.w * rinv) };
  *(u16x4*)(embn + r * ND + t * 4) = o;
}

// ---------------- K0b: tg[r] = clip(embn[r] . bf16(kern[:,lab[r]]) / ||kern[:,lab[r]]||)
__global__ __launch_bounds__(512) void k_tgt(const float* __restrict__ kern,
                                             const u16* __restrict__ embn,
                                             const int* __restrict__ lab,
                                             float* __restrict__ tgtws) {
  __shared__ float sd[512], sq[512];
  const int r = blockIdx.x, t = threadIdx.x;
  const int lb = lab[r];
  const float x = kern[(size_t)t * NC + lb];
  const float xb = bf2f(f2bf(x));                 // same quantization as GEMM B path
  const float a = bf2f(embn[r * ND + t]);
  sd[t] = a * xb; sq[t] = x * x;
  __syncthreads();
  for (int st = 256; st > 0; st >>= 1) {
    if (t < st) { sd[t] += sd[t + st]; sq[t] += sq[t + st]; }
    __syncthreads();
  }
  if (t == 0) {
    const float cinv = 1.0f / sqrtf(sq[0]);
    float v = sd[0] * cinv;
    v = fminf(fmaxf(v, -1.0f), 1.0f);
    tgtws[r] = v;
  }
}

// ---------------- K1: bf16 MFMA GEMM, fully fused epilogue ------------
// tile: M=256 x N=128, K-steps of 64. 8 waves = 2(M) x 4(N).
// Epilogue computes per-row sexp partial, argmax, global topk count,
// and sparse collect -- no cos matrix is ever materialized.
__global__ __launch_bounds__(512) void k_gemm(const float* __restrict__ kern,
                                              const u16* __restrict__ embn,
                                              const int* __restrict__ lab,
                                              const float* __restrict__ tgtws,
                                              u32* __restrict__ scal,
                                              u64* __restrict__ buf,
                                              u64* __restrict__ amax_g,
                                              float* __restrict__ sexp_part) {
  __shared__ u16 At[256 * 72];       // [m][k] pad 72
  __shared__ u16 Bt[64 * 132];       // [k][n] pad 132
  __shared__ float colp[16][128];    // column ssq partials
  __shared__ float tg_s[256];
  __shared__ int lab_s[256];
  __shared__ float sexp_lds[256];
  __shared__ u64 amax_lds[256];
  __shared__ u32 scnt[512];
  const int tid = threadIdx.x;
  const int lane = tid & 63;
  const int w = tid >> 6;
  const int mbase = (w >> 2) * 128, nbase = (w & 3) * 32;
  const int l15 = lane & 15, g = lane >> 4;
  const int cblk = blockIdx.x * 128;

  if (tid < 256) {
    tg_s[tid] = tgtws[tid];
    lab_s[tid] = lab[tid];
    sexp_lds[tid] = 0.f;
    amax_lds[tid] = 0ull;
  }

  f32x4 acc[8][2];
  #pragma unroll
  for (int i = 0; i < 8; ++i)
    for (int j = 0; j < 2; ++j) acc[i][j] = (f32x4){0.f, 0.f, 0.f, 0.f};

  const int am = tid >> 1, ah = (tid & 1) * 32;   // A staging
  const int bc4 = (tid & 31) * 4, bd = tid >> 5;  // B staging
  const int gc = cblk + bc4;
  const int gcs = (gc <= NC - 4) ? gc : (NC - 4); // clamp; OOB cols masked later
  float ss0 = 0.f, ss1 = 0.f, ss2 = 0.f, ss3 = 0.f;

  u16x8 areg[4];
  float4 breg[4];
  // prologue loads (K-step 0)
  #pragma unroll
  for (int j = 0; j < 4; ++j) areg[j] = *(const u16x8*)(embn + am * ND + ah + j * 8);
  #pragma unroll
  for (int i = 0; i < 4; ++i)
    breg[i] = *(const float4*)(kern + (size_t)(bd + i * 16) * NC + gcs);

  for (int ks = 0; ks < 8; ++ks) {
    // write staged regs to LDS (A verbatim, B fp32->bf16 + ssq)
    #pragma unroll
    for (int j = 0; j < 4; ++j) *(u16x8*)(At + am * 72 + ah + j * 8) = areg[j];
    #pragma unroll
    for (int i = 0; i < 4; ++i) {
      const int d = bd + i * 16;
      const float4 f = breg[i];
      ss0 += f.x * f.x; ss1 += f.y * f.y; ss2 += f.z * f.z; ss3 += f.w * f.w;
      u16x4 b4 = { f2bf(f.x), f2bf(f.y), f2bf(f.z), f2bf(f.w) };
      *(u16x4*)(Bt + d * 132 + bc4) = b4;
    }
    __syncthreads();
    // issue next K-step's loads early (in flight across the MFMA phase)
    if (ks < 7) {
      const int k0n = (ks + 1) * 64;
      #pragma unroll
      for (int j = 0; j < 4; ++j)
        areg[j] = *(const u16x8*)(embn + am * ND + k0n + ah + j * 8);
      #pragma unroll
      for (int i = 0; i < 4; ++i)
        breg[i] = *(const float4*)(kern + (size_t)(k0n + bd + i * 16) * NC + gcs);
    }
    #pragma unroll
    for (int kf = 0; kf < 2; ++kf) {
      bf16x8 bfr[2];
      #pragma unroll
      for (int nf = 0; nf < 2; ++nf) {
        const int n = nbase + nf * 16 + l15;
        u16x8 bu;
        #pragma unroll
        for (int i = 0; i < 8; ++i) bu[i] = Bt[(kf * 32 + g * 8 + i) * 132 + n];
        bfr[nf] = __builtin_bit_cast(bf16x8, bu);
      }
      #pragma unroll
      for (int mf = 0; mf < 8; ++mf) {
        const int m = mbase + mf * 16 + l15;
        bf16x8 av = *(const bf16x8*)(At + m * 72 + kf * 32 + g * 8);
        acc[mf][0] = __builtin_amdgcn_mfma_f32_16x16x32_bf16(av, bfr[0], acc[mf][0], 0, 0, 0);
        acc[mf][1] = __builtin_amdgcn_mfma_f32_16x16x32_bf16(av, bfr[1], acc[mf][1], 0, 0, 0);
      }
    }
    __syncthreads();
  }
  // column ssq tree reduce
  colp[bd][bc4 + 0] = ss0; colp[bd][bc4 + 1] = ss1;
  colp[bd][bc4 + 2] = ss2; colp[bd][bc4 + 3] = ss3;
  __syncthreads();
  for (int st = 8; st > 0; st >>= 1) {
    if (bd < st) {
      colp[bd][bc4 + 0] += colp[bd + st][bc4 + 0];
      colp[bd][bc4 + 1] += colp[bd + st][bc4 + 1];
      colp[bd][bc4 + 2] += colp[bd + st][bc4 + 2];
      colp[bd][bc4 + 3] += colp[bd + st][bc4 + 3];
    }
    __syncthreads();
  }

  // ---- fused epilogue: stats straight from accumulators ----
  float cinv[2];
  #pragma unroll
  for (int nf = 0; nf < 2; ++nf) cinv[nf] = 1.0f / sqrtf(colp[0][nbase + nf * 16 + l15]);

  u32 cnt_t = 0;
  #pragma unroll
  for (int mf = 0; mf < 8; ++mf) {
    #pragma unroll
    for (int r = 0; r < 4; ++r) {
      const int row = mbase + mf * 16 + g * 4 + r;
      const float tg = tg_s[row];
      const int lb = lab_s[row];
      float e = 0.f; u64 pk = 0ull;
      #pragma unroll
      for (int nf = 0; nf < 2; ++nf) {
        const int c = cblk + nbase + nf * 16 + l15;
        if (c < NC) {
          float v = acc[mf][nf][r] * cinv[nf];
          v = fminf(fmaxf(v, -1.0f), 1.0f);
          e += exp2f(EXP2K * v);
          const u64 p = ((u64)ordkey(v) << 32) | (u32)(0xFFFFFFFFu - (u32)c);
          if (p > pk) pk = p;
          if (c != lb) {
            if (v > tg) cnt_t++;
            else if (v >= THRC) {
              u32 pos = atomicAdd(&scal[1], 1u);
              if (pos < CAP) buf[pos] = ((u64)ordkey(v) << 32) | (u32)row;
            }
          }
        }
      }
      // reduce over the 16 lanes sharing this row (lane bits 0..3)
      #pragma unroll
      for (int m = 1; m < 16; m <<= 1) {
        e += __shfl_xor(e, m, 64);
        u64 o = __shfl_xor(pk, m, 64);
        if (o > pk) pk = o;
      }
      if (l15 == 0) {
        atomicAdd(&sexp_lds[row], e);
        atomicMax(&amax_lds[row], pk);
      }
    }
  }
  scnt[tid] = cnt_t;
  __syncthreads();
  for (int st = 256; st > 0; st >>= 1) {
    if (tid < st) scnt[tid] += scnt[tid + st];
    __syncthreads();
  }
  if (tid == 0) atomicAdd(&scal[0], scnt[0]);
  if (tid < 256) {
    sexp_part[(size_t)tid * 800 + blockIdx.x] = sexp_lds[tid];
    atomicMax(&amax_g[tid], amax_lds[tid]);
  }
}

// ---------------- K2: deterministic per-row sexp reduction ------------
__global__ void k_reduce(const float* __restrict__ part, float* __restrict__ sexpws) {
  __shared__ float s[256];
  const int r = blockIdx.x, t = threadIdx.x;
  float a = 0.f;
  for (int b = t; b < NBLK; b += 256) a += part[(size_t)r * 800 + b];
  s[t] = a;
  __syncthreads();
  for (int st = 128; st > 0; st >>= 1) { if (t < st) s[t] += s[t + st]; __syncthreads(); }
  if (t == 0) sexpws[r] = s[0];
}

// ---------------- K3: finisher (1 block): select th + stats + loss ----
__global__ __launch_bounds__(1024) void k_finish(const u64* __restrict__ buf,
                                                 const u32* __restrict__ scal,
                                                 const int* __restrict__ lab,
                                                 const float* __restrict__ tgtws,
                                                 const float* __restrict__ sexpws,
                                                 const u64* __restrict__ amax_g,
                                                 float* __restrict__ out) {
  __shared__ u32 hist[4096];
  __shared__ u32 s[1024], cs[1024];
  __shared__ u32 sb1, sr1, sb2, sr2, sthkey, lcnt;
  __shared__ u64 lbuf[512];
  __shared__ float rl[256], ra[256];
  const int tid = threadIdx.x;
  const int n = (int)min(scal[1], (u32)CAP);
  const int topk = (int)scal[0];
  int a = 25599744 - topk; if (a < 0) a = 0;               // B*(C-1)
  int k = (int)ceilf((1.0f / 99999.0f) * (float)a);        // mirror ref f32 math
  if (k < 1) k = 1;

  if (tid == 0) { sb1 = 0; sr1 = 1; sb2 = 0; sr2 = 1; lcnt = 0; }
  // ---- level 1: key bits 31..20 ----
  for (int i = tid; i < 4096; i += 1024) hist[i] = 0;
  __syncthreads();
  for (int i = tid; i < n; i += 1024) atomicAdd(&hist[(u32)(buf[i] >> 52)], 1u);
  __syncthreads();
  {
    u32 h[4]; u32 c = 0;
    #pragma unroll
    for (int j = 0; j < 4; ++j) { h[j] = hist[tid * 4 + j]; c += h[j]; }
    cs[tid] = c; s[tid] = c;
    __syncthreads();
    for (int off = 1; off < 1024; off <<= 1) {
      u32 v = (tid + off < 1024) ? s[tid + off] : 0u;
      __syncthreads(); s[tid] += v; __syncthreads();
    }
    u32 incl = s[tid], excl = incl - cs[tid];
    if ((int)excl < k && (int)incl >= k) {
      u32 cum = excl;
      for (int j = 3; j >= 0; --j) {
        cum += h[j];
        if ((int)cum >= k) { sb1 = tid * 4 + j; sr1 = (u32)k - (cum - h[j]); break; }
      }
    }
  }
  __syncthreads();
  const u32 b1 = sb1, r1 = sr1;
  // ---- level 2: key bits 19..8 ----
  for (int i = tid; i < 4096; i += 1024) hist[i] = 0;
  __syncthreads();
  for (int i = tid; i < n; i += 1024) {
    u32 key = (u32)(buf[i] >> 32);
    if ((key >> 20) == b1) atomicAdd(&hist[(key >> 8) & 4095u], 1u);
  }
  __syncthreads();
  {
    u32 h[4]; u32 c = 0;
    #pragma unroll
    for (int j = 0; j < 4; ++j) { h[j] = hist[tid * 4 + j]; c += h[j]; }
    cs[tid] = c; s[tid] = c;
    __syncthreads();
    for (int off = 1; off < 1024; off <<= 1) {
      u32 v = (tid + off < 1024) ? s[tid + off] : 0u;
      __syncthreads(); s[tid] += v; __syncthreads();
    }
    u32 incl = s[tid], excl = incl - cs[tid];
    if (excl < r1 && incl >= r1) {
      u32 cum = excl;
      for (int j = 3; j >= 0; --j) {
        cum += h[j];
        if (cum >= r1) { sb2 = tid * 4 + j; sr2 = r1 - (cum - h[j]); break; }
      }
    }
  }
  __syncthreads();
  const u32 b2 = sb2, r2 = sr2;
  // ---- level 3: key bits 7..0 ----
  for (int i = tid; i < 256; i += 1024) hist[i] = 0;
  __syncthreads();
  const u32 pfx = (b1 << 12) | b2;
  for (int i = tid; i < n; i += 1024) {
    u32 key = (u32)(buf[i] >> 32);
    if ((key >> 8) == pfx) atomicAdd(&hist[key & 255u], 1u);
  }
  __syncthreads();
  if (tid == 0) {
    u32 cum = 0, b3 = 0;
    for (int j = 255; j >= 0; --j) { cum += hist[j]; if (cum >= r2) { b3 = (u32)j; break; } }
    sthkey = (b1 << 20) | (b2 << 8) | b3;
  }
  __syncthreads();
  const u32 thk = sthkey;
  // ---- collect strictly-greater entries (k-1 < 512 of them) ----
  for (int i = tid; i < n; i += 1024) {
    u64 e = buf[i];
    if ((u32)(e >> 32) > thk) { u32 p = atomicAdd(&lcnt, 1u); if (p < 512) lbuf[p] = e; }
  }
  __syncthreads();
  const int m = (int)min(lcnt, 512u);
  if (tid < 256) {
    const int r = tid;
    int cnt = 0; float ssq = 0.f;
    for (int j = 0; j < m; ++j) {
      u64 e = lbuf[j];
      if ((u32)(e & 0xFFFFFFFFu) == (u32)r) {
        float v = inv_ordkey((u32)(e >> 32));
        cnt++; ssq += v * v;
      }
    }
    const float tg = tgtws[r];
    const float times = fmaxf((float)cnt, 1.0f);
    const float nm = ssq / times;
    const float tgm = (tg - 0.4f) - (1.0f + tg) * nm;
    const float sexp = sexpws[r] - exp2f(EXP2K * tg) + exp2f(EXP2K * tgm);
    rl[r] = logf(sexp) - 64.0f * tgm;
    const u32 acol = 0xFFFFFFFFu - (u32)(amax_g[r] & 0xFFFFFFFFu);
    ra[r] = (acol == (u32)lab[r]) ? 1.0f : 0.0f;
  }
  __syncthreads();
  for (int st = 128; st > 0; st >>= 1) {
    if (tid < st) { rl[tid] += rl[tid + st]; ra[tid] += ra[tid + st]; }
    __syncthreads();
  }
  if (tid == 0) { out[0] = rl[0] * (1.0f / 256.0f); out[1] = ra[0] * (1.0f / 256.0f); }
}

extern "C" void kernel_launch(void* const* d_in, const int* in_sizes, int n_in,
                              void* d_out, int out_size, void* d_ws, size_t ws_size,
                              hipStream_t stream) {
  const float* emb = (const float*)d_in[0];
  const int* lab = (const int*)d_in[1];
  const float* kern = (const float*)d_in[2];
  float* out = (float*)d_out;
  char* ws = (char*)d_ws;

  u16* embn = (u16*)(ws + OFF_EMBN);
  float* tgtws = (float*)(ws + OFF_TGT);
  float* sexpws = (float*)(ws + OFF_SEXP);
  u64* amax_g = (u64*)(ws + OFF_AMAX);
  u32* scal = (u32*)(ws + OFF_SCAL);   // [0]=topk [1]=bufcnt
  float* part = (float*)(ws + OFF_PART);
  u64* buf = (u64*)(ws + OFF_BUF);

  hipMemsetAsync(ws + OFF_AMAX, 0, 2064, stream);  // amax (2048) + scal (16)
  k_prep<<<NB, 128, 0, stream>>>(emb, embn);
  k_tgt<<<NB, 512, 0, stream>>>(kern, embn, lab, tgtws);
  k_gemm<<<NBLK, 512, 0, stream>>>(kern, embn, lab, tgtws, scal, buf, amax_g, part);
  k_reduce<<<NB, 256, 0, stream>>>(part, sexpws);
  k_finish<<<1, 1024, 0, stream>>>(buf, scal, lab, tgtws, sexpws, amax_g, out);
}